// Round 2
// baseline (334.222 us; speedup 1.0000x reference)
//
#include <hip/hip_runtime.h>
#include <hip/hip_bf16.h>

typedef __bf16 bf16x8 __attribute__((ext_vector_type(8)));
typedef unsigned short ushort8 __attribute__((ext_vector_type(8)));
typedef unsigned short ushort4v __attribute__((ext_vector_type(4)));
typedef float f32x4 __attribute__((ext_vector_type(4)));

__device__ __forceinline__ unsigned short f2bf(float f) {
    union { float f; unsigned int i; } v;
    v.f = f;
    unsigned int i = v.i;
    i += 0x7fffu + ((i >> 16) & 1u);  // round-to-nearest-even
    return (unsigned short)(i >> 16);
}

__device__ __forceinline__ float fast_tanh(float x) {
    // tanh(x) = 1 - 2/(exp(2x)+1); saturates correctly for large |x|
    float e = __expf(2.0f * x);
    return 1.0f - 2.0f * __builtin_amdgcn_rcpf(e + 1.0f);
}

// Pre-round the three weight matrices fp32 -> bf16 into workspace.
// sizes: W_enc 262144, W_dec 262144, W_out 256000; total/4 = 195072 thr.
__global__ __launch_bounds__(256) void convert_kernel(
    const float* __restrict__ We, const float* __restrict__ Wd,
    const float* __restrict__ Wo,
    unsigned short* __restrict__ oWe, unsigned short* __restrict__ oWd,
    unsigned short* __restrict__ oWo)
{
    const int i = (blockIdx.x * 256 + threadIdx.x) * 4;
    const float* src; unsigned short* dst; int off;
    if (i < 262144)      { src = We; dst = oWe; off = i; }
    else if (i < 524288) { src = Wd; dst = oWd; off = i - 262144; }
    else if (i < 780288) { src = Wo; dst = oWo; off = i - 524288; }
    else return;
    const float4 v = *(const float4*)(src + off);
    ushort4v p;
    p.x = f2bf(v.x); p.y = f2bf(v.y); p.z = f2bf(v.z); p.w = f2bf(v.w);
    *(ushort4v*)(dst + off) = p;
}

// C = A(Ma x 512, f32) @ Wbf^T(512 x 512, bf16) + b(f32)  -> fp32 out.
// block: 256 thr = 4 waves; tile 64 rows; wave w computes 64 x 128 cols.
__global__ __launch_bounds__(256, 2) void proj_kernel(
    const float* __restrict__ A,
    const unsigned short* __restrict__ W,   // bf16, 512x512, k-contig
    const float* __restrict__ bias,
    float* __restrict__ outp,
    int Ma)
{
    __shared__ unsigned short tile[64 * 520];  // 64 rows x 512 k (bf16), stride 520
    const int tid = threadIdx.x;
    const int r0 = blockIdx.x * 64;

    {   // stage A tile fp32 -> bf16: 4 threads per row, 8-elem chunks
        const int row = tid >> 2, q = tid & 3;
        int gr = r0 + row;
        if (gr >= Ma) gr = Ma - 1;  // clamp (stores skipped later)
        const float* src = A + (size_t)gr * 512;
        ushort8* dst = (ushort8*)(tile + row * 520);
        #pragma unroll
        for (int i = 0; i < 16; ++i) {
            const int c = q + i * 4;
            const int k = c * 8;
            const float4 a0 = *(const float4*)(src + k);
            const float4 a1 = *(const float4*)(src + k + 4);
            ushort8 pk;
            pk[0] = f2bf(a0.x); pk[1] = f2bf(a0.y); pk[2] = f2bf(a0.z); pk[3] = f2bf(a0.w);
            pk[4] = f2bf(a1.x); pk[5] = f2bf(a1.y); pk[6] = f2bf(a1.z); pk[7] = f2bf(a1.w);
            dst[c] = pk;
        }
    }
    __syncthreads();

    const int wave = tid >> 6, lane = tid & 63;
    const int lrow = lane & 15;
    const int lk8  = (lane >> 4) * 8;
    const int j0   = wave * 128;

    f32x4 acc[4][8];
    #pragma unroll
    for (int mi = 0; mi < 4; ++mi)
        #pragma unroll
        for (int ji = 0; ji < 8; ++ji)
            acc[mi][ji] = (f32x4){0.f, 0.f, 0.f, 0.f};

    const unsigned short* wbase = W + (size_t)(j0 + lrow) * 512 + lk8;
    const unsigned short* abase = tile + lrow * 520 + lk8;

    for (int kk = 0; kk < 512; kk += 32) {
        bf16x8 a[4], b[8];
        #pragma unroll
        for (int mi = 0; mi < 4; ++mi)
            a[mi] = *(const bf16x8*)(abase + mi * 16 * 520 + kk);
        #pragma unroll
        for (int ji = 0; ji < 8; ++ji)
            b[ji] = *(const bf16x8*)(wbase + (size_t)ji * 16 * 512 + kk);
        #pragma unroll
        for (int mi = 0; mi < 4; ++mi)
            #pragma unroll
            for (int ji = 0; ji < 8; ++ji)
                acc[mi][ji] = __builtin_amdgcn_mfma_f32_16x16x32_bf16(
                    a[mi], b[ji], acc[mi][ji], 0, 0, 0);
    }

    const int crow = (lane >> 4) * 4;
    const int ccol = lane & 15;
    #pragma unroll
    for (int ji = 0; ji < 8; ++ji) {
        const int col = j0 + ji * 16 + ccol;
        const float bv = bias[col];
        #pragma unroll
        for (int mi = 0; mi < 4; ++mi)
            #pragma unroll
            for (int rg = 0; rg < 4; ++rg) {
                const int gr = r0 + mi * 16 + crow + rg;
                if (gr < Ma) outp[(size_t)gr * 512 + col] = acc[mi][ji][rg] + bv;
            }
    }
}

// out[r, v] = sum_k tanh(enc[n,t,k] + dec[n,u,k]) * Wout[v,k] + bout[v]
// r = (n*200 + t)*50 + u, 64 rows/block, 1250 blocks. fp32 output.
__global__ __launch_bounds__(256, 2) void joiner_kernel(
    const float* __restrict__ encp,          // 1600 x 512 f32 (ws)
    const float* __restrict__ decp,          // 400 x 512 f32 (ws)
    const unsigned short* __restrict__ Wout, // 500 x 512 bf16 (ws)
    const float* __restrict__ bout,          // 500 f32
    float* __restrict__ out)                 // 80000 x 500 f32
{
    __shared__ unsigned short tile[64 * 520];
    const int tid = threadIdx.x;
    const int r0 = blockIdx.x * 64;

    {   // phase 1: x-tile = tanh(enc+dec) -> bf16, computed ONCE, kept in LDS
        const int row = tid >> 2, q = tid & 3;
        const int r = r0 + row;
        const int n = r / 10000;
        const int rem = r % 10000;
        const int t = rem / 50;
        const int u = rem - t * 50;
        const float* erow = encp + (size_t)(n * 200 + t) * 512;
        const float* drow = decp + (size_t)(n * 50 + u) * 512;
        ushort8* dst = (ushort8*)(tile + row * 520);
        #pragma unroll
        for (int i = 0; i < 16; ++i) {
            const int c = q + i * 4;
            const int k = c * 8;
            const float4 ev0 = *(const float4*)(erow + k);
            const float4 ev1 = *(const float4*)(erow + k + 4);
            const float4 dv0 = *(const float4*)(drow + k);
            const float4 dv1 = *(const float4*)(drow + k + 4);
            float xs[8] = {ev0.x + dv0.x, ev0.y + dv0.y, ev0.z + dv0.z, ev0.w + dv0.w,
                           ev1.x + dv1.x, ev1.y + dv1.y, ev1.z + dv1.z, ev1.w + dv1.w};
            ushort8 pk;
            #pragma unroll
            for (int j = 0; j < 8; ++j) pk[j] = f2bf(fast_tanh(xs[j]));
            dst[c] = pk;
        }
    }
    __syncthreads();

    // phase 2: barrier-free K-loop. Wave w owns v in [w*128, w*128+128).
    const int wave = tid >> 6, lane = tid & 63;
    const int lrow = lane & 15;
    const int lk8  = (lane >> 4) * 8;
    const int v0   = wave * 128;

    f32x4 acc[4][8];
    #pragma unroll
    for (int mi = 0; mi < 4; ++mi)
        #pragma unroll
        for (int ji = 0; ji < 8; ++ji)
            acc[mi][ji] = (f32x4){0.f, 0.f, 0.f, 0.f};

    const unsigned short* wrow[8];
    #pragma unroll
    for (int ji = 0; ji < 8; ++ji) {
        int v = v0 + ji * 16 + lrow;
        if (v > 499) v = 499;  // clamp: cols >=500 computed but never stored
        wrow[ji] = Wout + (size_t)v * 512 + lk8;
    }
    const unsigned short* abase = tile + lrow * 520 + lk8;

    for (int kk = 0; kk < 512; kk += 32) {
        bf16x8 a[4], b[8];
        #pragma unroll
        for (int mi = 0; mi < 4; ++mi)
            a[mi] = *(const bf16x8*)(abase + mi * 16 * 520 + kk);
        #pragma unroll
        for (int ji = 0; ji < 8; ++ji)
            b[ji] = *(const bf16x8*)(wrow[ji] + kk);
        #pragma unroll
        for (int mi = 0; mi < 4; ++mi)
            #pragma unroll
            for (int ji = 0; ji < 8; ++ji)
                acc[mi][ji] = __builtin_amdgcn_mfma_f32_16x16x32_bf16(
                    a[mi], b[ji], acc[mi][ji], 0, 0, 0);
    }

    const int crow = (lane >> 4) * 4;
    const int ccol = lane & 15;
    #pragma unroll
    for (int ji = 0; ji < 8; ++ji) {
        const int v = v0 + ji * 16 + ccol;
        if (v < 500) {
            const float bv = bout[v];
            #pragma unroll
            for (int mi = 0; mi < 4; ++mi)
                #pragma unroll
                for (int rg = 0; rg < 4; ++rg) {
                    const size_t gr = (size_t)(r0 + mi * 16 + crow + rg);
                    out[gr * 500 + v] = acc[mi][ji][rg] + bv;
                }
        }
    }
}

extern "C" void kernel_launch(void* const* d_in, const int* in_sizes, int n_in,
                              void* d_out, int out_size, void* d_ws, size_t ws_size,
                              hipStream_t stream) {
    (void)in_sizes; (void)n_in; (void)out_size; (void)ws_size;
    const float* enc_in = (const float*)d_in[0]; // 8x200x512 f32
    const float* dec_in = (const float*)d_in[1]; // 8x50x512 f32
    const float* W_enc  = (const float*)d_in[2]; // 512x512 f32
    const float* b_enc  = (const float*)d_in[3]; // 512 f32
    const float* W_dec  = (const float*)d_in[4]; // 512x512 f32
    const float* b_dec  = (const float*)d_in[5]; // 512 f32
    const float* W_out  = (const float*)d_in[6]; // 500x512 f32
    const float* b_out  = (const float*)d_in[7]; // 500 f32
    float* out = (float*)d_out;                  // 8x200x50x500 f32

    float* ws = (float*)d_ws;
    float* enc_proj = ws;                               // 1600*512 f32
    float* dec_proj = ws + 819200;                      // 400*512 f32
    unsigned short* wenc_bf = (unsigned short*)(ws + 1024000);  // 262144 bf16
    unsigned short* wdec_bf = wenc_bf + 262144;                 // 262144 bf16
    unsigned short* wout_bf = wdec_bf + 262144;                 // 256000 bf16

    hipLaunchKernelGGL(convert_kernel, dim3(762), dim3(256), 0, stream,
                       W_enc, W_dec, W_out, wenc_bf, wdec_bf, wout_bf);
    hipLaunchKernelGGL(proj_kernel, dim3(25), dim3(256), 0, stream,
                       enc_in, wenc_bf, b_enc, enc_proj, 1600);
    hipLaunchKernelGGL(proj_kernel, dim3(7), dim3(256), 0, stream,
                       dec_in, wdec_bf, b_dec, dec_proj, 400);
    hipLaunchKernelGGL(joiner_kernel, dim3(1250), dim3(256), 0, stream,
                       enc_proj, dec_proj, wout_bf, b_out, out);
}